// Round 8
// baseline (173.388 us; speedup 1.0000x reference)
//
#include <hip/hip_runtime.h>
#include <math.h>

// Problem constants
#define N_IMG 16
#define C_CH 3
#define H_DIM 512
#define W_DIM 512
#define HW (H_DIM * W_DIM)              // 262144
#define KS 7
#define PAD 3

// Round-0 proven structure: 64x64 output tile per block, 3-halo each side,
// scalar staging with reflect, 16 px/thread ring-buffer sliding window.
// Round-8 deltas: (1) bijective XCD swizzle (1024%8==0) so each XCD owns 2
// whole images -> staging/halo re-reads are L2-local; (2) k_final is gone:
// the LAST block to finish (atomicAdd on a ws counter, threadfence release/
// acquire) reduces the 1024 partials in-kernel -> saves one launch gap +
// single-block dispatch.
#define TS 64
#define TILE (TS + 2 * PAD)             // 70
#define TSTRIDE 72                      // LDS row stride (floats)
#define TPB 256
#define TILES_PER_IMG ((H_DIM / TS) * (W_DIM / TS))   // 64
#define NBLOCKS (N_IMG * TILES_PER_IMG)               // 1024

// ws layout: pr/pr2/pc [NBLOCKS] float partials, then an int counter.

__global__ __launch_bounds__(TPB) void k_fused(const float* __restrict__ pred,
                                               const float* __restrict__ targ,
                                               float* __restrict__ pr,
                                               float* __restrict__ pr2,
                                               float* __restrict__ pc,
                                               int* __restrict__ cnt,
                                               float* __restrict__ out) {
    __shared__ float tile[TILE * TSTRIDE];

    // Bijective XCD swizzle: XCD x owns blocks [x*128, x*128+127] = 2 images.
    const int bid = ((blockIdx.x & 7) << 7) | (blockIdx.x >> 3);
    const int n   = bid >> 6;              // 64 tiles per image
    const int t   = bid & 63;
    const int by  = t >> 3;                // 8 tiles per dim
    const int bx  = t & 7;
    const int tid = threadIdx.x;

    const float* p0 = pred + (size_t)n * C_CH * HW;
    const float* p1 = p0 + HW;
    const float* p2 = p1 + HW;
    const float* q0 = targ + (size_t)n * C_CH * HW;
    const float* q1 = q0 + HW;
    const float* q2 = q1 + HW;

    // --- residual tile with reflect halo: 70*70 = 4900 = 19*256 + 36 ---
    const int y0 = by * TS - PAD;
    const int x0 = bx * TS - PAD;
#pragma unroll 4
    for (int it = 0; it < 19; ++it) {
        const int i  = tid + it * TPB;
        const int ly = i / TILE;
        const int lx = i - ly * TILE;
        int gy = y0 + ly;
        int gx = x0 + lx;
        gy = (gy < 0) ? -gy : ((gy >= H_DIM) ? (2 * H_DIM - 2 - gy) : gy);
        gx = (gx < 0) ? -gx : ((gx >= W_DIM) ? (2 * W_DIM - 2 - gx) : gx);
        const int off = gy * W_DIM + gx;
        tile[ly * TSTRIDE + lx] = fabsf(q0[off] - p0[off])
                                + fabsf(q1[off] - p1[off])
                                + fabsf(q2[off] - p2[off]);
    }
    if (tid < 36) {
        const int i  = tid + 19 * TPB;
        const int ly = i / TILE;
        const int lx = i - ly * TILE;
        int gy = y0 + ly;
        int gx = x0 + lx;
        gy = (gy < 0) ? -gy : ((gy >= H_DIM) ? (2 * H_DIM - 2 - gy) : gy);
        gx = (gx < 0) ? -gx : ((gx >= W_DIM) ? (2 * W_DIM - 2 - gx) : gx);
        const int off = gy * W_DIM + gx;
        tile[ly * TSTRIDE + lx] = fabsf(q0[off] - p0[off])
                                + fabsf(q1[off] - p1[off])
                                + fabsf(q2[off] - p2[off]);
    }
    __syncthreads();

    // --- 16 vertically-adjacent output pixels per thread ---
    const int tx  = tid & 63;              // output column 0..63
    const int ty0 = (tid >> 6) << 4;       // output rows ty0..ty0+15

    // ring buffer of per-row horizontal sums over the 7-wide window
    float rS[KS], rSS[KS];
    float S = 0.f, SS = 0.f;
#pragma unroll
    for (int dy = 0; dy < KS; ++dy) {
        float s = 0.f, ss = 0.f;
#pragma unroll
        for (int j = 0; j < KS; ++j) {
            const float v = tile[(ty0 + dy) * TSTRIDE + tx + j];
            s  += v;
            ss += v * v;
        }
        rS[dy] = s; rSS[dy] = ss;
        S += s; SS += ss;
    }

    float acc_r = 0.f, acc_r2 = 0.f, acc_c = 0.f;

#pragma unroll
    for (int k = 0; k < 16; ++k) {
        if (k > 0) {
            // slide down one row: add row ty0+6+k, drop oldest ring slot
            float s = 0.f, ss = 0.f;
#pragma unroll
            for (int j = 0; j < KS; ++j) {
                const float v = tile[(ty0 + 6 + k) * TSTRIDE + tx + j];
                s  += v;
                ss += v * v;
            }
            const int slot = (k - 1) % KS;   // compile-time after unroll
            S  += s  - rS[slot];
            SS += ss - rSS[slot];
            rS[slot] = s; rSS[slot] = ss;
        }
        const float pix_var = (SS - S * S * (1.0f / 49.0f)) * (1.0f / 48.0f);
        const float center  = tile[(ty0 + 3 + k) * TSTRIDE + tx + 3];

        acc_r  += center;
        acc_r2 += center * center;
        acc_c  += pix_var * center;
    }

    // --- block reduce 3 floats (wave shuffle -> LDS -> thread 0) ---
#pragma unroll
    for (int off = 32; off > 0; off >>= 1) {
        acc_r  += __shfl_down(acc_r,  off);
        acc_r2 += __shfl_down(acc_r2, off);
        acc_c  += __shfl_down(acc_c,  off);
    }
    __shared__ float sh_r[4], sh_r2[4], sh_c[4];
    const int lane = tid & 63;
    const int wave = tid >> 6;
    if (lane == 0) { sh_r[wave] = acc_r; sh_r2[wave] = acc_r2; sh_c[wave] = acc_c; }
    __syncthreads();

    __shared__ int s_last;
    if (tid == 0) {
        pr [bid] = sh_r [0] + sh_r [1] + sh_r [2] + sh_r [3];
        pr2[bid] = sh_r2[0] + sh_r2[1] + sh_r2[2] + sh_r2[3];
        pc [bid] = sh_c [0] + sh_c [1] + sh_c [2] + sh_c [3];
        __threadfence();                   // release: partials visible device-wide
        const int old = atomicAdd(cnt, 1); // device-scope by default
        s_last = (old == NBLOCKS - 1);
    }
    __syncthreads();

    // --- last-arriving block finalizes (replaces k_final kernel) ---
    if (s_last) {
        __threadfence();                   // acquire: see all blocks' partials
        __shared__ double sh[N_IMG];
        // 4 waves; wave w handles images w*4 .. w*4+3 (lane = partial index)
#pragma unroll
        for (int i = 0; i < 4; ++i) {
            const int img = wave * 4 + i;
            const int idx = img * TILES_PER_IMG + lane;
            double R  = (double)pr [idx];
            double R2 = (double)pr2[idx];
            double Cs = (double)pc [idx];
#pragma unroll
            for (int off = 32; off > 0; off >>= 1) {
                R  += __shfl_down(R,  off);
                R2 += __shfl_down(R2, off);
                Cs += __shfl_down(Cs, off);
            }
            if (lane == 0) {
                const double pvar = (R2 - R * R / (double)HW) / (double)(HW - 1);
                sh[img] = pow(pvar, 0.2) * Cs;
            }
        }
        __syncthreads();
        if (tid == 0) {
            double s = 0.0;
            for (int i = 0; i < N_IMG; ++i) s += sh[i];
            out[0] = (float)(s / ((double)N_IMG * C_CH * HW));
        }
    }
}

extern "C" void kernel_launch(void* const* d_in, const int* in_sizes, int n_in,
                              void* d_out, int out_size, void* d_ws, size_t ws_size,
                              hipStream_t stream) {
    const float* pred = (const float*)d_in[0];
    const float* targ = (const float*)d_in[1];

    float* pr  = (float*)d_ws;
    float* pr2 = pr  + NBLOCKS;
    float* pc  = pr2 + NBLOCKS;
    int*   cnt = (int*)(pc + NBLOCKS);
    float* out = (float*)d_out;

    hipMemsetAsync(cnt, 0, sizeof(int), stream);   // zero the arrival counter
    k_fused<<<NBLOCKS, TPB, 0, stream>>>(pred, targ, pr, pr2, pc, cnt, out);
}

// Round 9
// 128.053 us; speedup vs baseline: 1.3540x; 1.3540x over previous
//
#include <hip/hip_runtime.h>
#include <math.h>

// Problem constants
#define N_IMG 16
#define C_CH 3
#define H_DIM 512
#define W_DIM 512
#define HW (H_DIM * W_DIM)              // 262144
#define KS 7
#define PAD 3

// Best-known composition (session rounds 0/1/2):
//  - round-0 structure: 64x64 output tile per block, 1024 blocks, separate
//    k_final launch (NO grid-sync, NO atomic tail, NO XCD swizzle — all
//    three measured as regressions in R1/R8).
//  - round-1 staging: LDS tile spans 72 cols with 16B-aligned x-origin
//    (xa = bx*64-4), so interior tiles (by,bx in [1,6]) stage as pure
//    float4 loads (1260 groups), edge tiles keep scalar reflect.
#define TS 64
#define TROWS 70                        // 64 + 2*3 halo rows
#define TCOLS 72                        // 64 + 8 cols (aligned halo)
#define TSTRIDE 72                      // LDS row stride (floats)
#define TPB 256
#define NGROUPS (TROWS * 18)            // 1260 float4-groups per tile
#define TILES_PER_IMG ((H_DIM / TS) * (W_DIM / TS))   // 64
#define NBLOCKS (N_IMG * TILES_PER_IMG)               // 1024

// ws layout: pr/pr2/pc [NBLOCKS] float partials (no atomics anywhere)

__global__ __launch_bounds__(TPB) void k_fused(const float* __restrict__ pred,
                                               const float* __restrict__ targ,
                                               float* __restrict__ pr,
                                               float* __restrict__ pr2,
                                               float* __restrict__ pc) {
    __shared__ float tile[TROWS * TSTRIDE];

    const int bid = blockIdx.x;            // natural order (no swizzle)
    const int n   = bid >> 6;              // 64 tiles per image
    const int t   = bid & 63;
    const int by  = t >> 3;                // 8 tiles per dim
    const int bx  = t & 7;
    const int tid = threadIdx.x;

    const float* p0 = pred + (size_t)n * C_CH * HW;
    const float* p1 = p0 + HW;
    const float* p2 = p1 + HW;
    const float* q0 = targ + (size_t)n * C_CH * HW;
    const float* q1 = q0 + HW;
    const float* q2 = q1 + HW;

    const int y0 = by * TS - PAD;          // gy of tile row 0
    const int xa = bx * TS - 4;            // gx of tile col 0, 16B-aligned

    if (by >= 1 && by <= 6 && bx >= 1 && bx <= 6) {
        // --- fast path (interior tile, no reflect): 70 rows x 18 float4 ---
        // rows y0..y0+69 in [61,450]; cols xa..xa+71 in [60,451] -> in-bounds
#pragma unroll
        for (int it = 0; it < 5; ++it) {
            const int i = tid + it * TPB;
            if (i < NGROUPS) {
                const int r = i / 18;
                const int g = i - r * 18;
                const int goff = (y0 + r) * W_DIM + xa + g * 4;   // aligned
                const float4 a0 = *(const float4*)(p0 + goff);
                const float4 a1 = *(const float4*)(p1 + goff);
                const float4 a2 = *(const float4*)(p2 + goff);
                const float4 b0 = *(const float4*)(q0 + goff);
                const float4 b1 = *(const float4*)(q1 + goff);
                const float4 b2 = *(const float4*)(q2 + goff);
                float4 res;
                res.x = fabsf(b0.x - a0.x) + fabsf(b1.x - a1.x) + fabsf(b2.x - a2.x);
                res.y = fabsf(b0.y - a0.y) + fabsf(b1.y - a1.y) + fabsf(b2.y - a2.y);
                res.z = fabsf(b0.z - a0.z) + fabsf(b1.z - a1.z) + fabsf(b2.z - a2.z);
                res.w = fabsf(b0.w - a0.w) + fabsf(b1.w - a1.w) + fabsf(b2.w - a2.w);
                *(float4*)&tile[r * TSTRIDE + g * 4] = res;
            }
        }
    } else {
        // --- edge path (reflect): 70*72 = 5040 = 19*256 + 176 scalar px ---
#pragma unroll 4
        for (int it = 0; it < 20; ++it) {
            const int i = tid + it * TPB;
            if (i < TROWS * TCOLS) {
                const int ly = i / TCOLS;
                const int lx = i - ly * TCOLS;
                int gy = y0 + ly;
                int gx = xa + lx;
                gy = (gy < 0) ? -gy : ((gy >= H_DIM) ? (2 * H_DIM - 2 - gy) : gy);
                gx = (gx < 0) ? -gx : ((gx >= W_DIM) ? (2 * W_DIM - 2 - gx) : gx);
                const int off = gy * W_DIM + gx;
                tile[ly * TSTRIDE + lx] = fabsf(q0[off] - p0[off])
                                        + fabsf(q1[off] - p1[off])
                                        + fabsf(q2[off] - p2[off]);
            }
        }
    }
    __syncthreads();

    // --- 16 vertically-adjacent output pixels per thread ---
    // output col tx -> LDS cols tx+1 .. tx+7 (center tx+4)
    const int tx  = tid & 63;              // output column 0..63
    const int ty0 = (tid >> 6) << 4;       // output rows ty0..ty0+15

    // ring buffer of per-row horizontal sums over the 7-wide window
    float rS[KS], rSS[KS];
    float S = 0.f, SS = 0.f;
#pragma unroll
    for (int dy = 0; dy < KS; ++dy) {
        float s = 0.f, ss = 0.f;
#pragma unroll
        for (int j = 0; j < KS; ++j) {
            const float v = tile[(ty0 + dy) * TSTRIDE + tx + 1 + j];
            s  += v;
            ss += v * v;
        }
        rS[dy] = s; rSS[dy] = ss;
        S += s; SS += ss;
    }

    float acc_r = 0.f, acc_r2 = 0.f, acc_c = 0.f;

#pragma unroll
    for (int k = 0; k < 16; ++k) {
        if (k > 0) {
            // slide down one row: add row ty0+6+k, drop oldest ring slot
            float s = 0.f, ss = 0.f;
#pragma unroll
            for (int j = 0; j < KS; ++j) {
                const float v = tile[(ty0 + 6 + k) * TSTRIDE + tx + 1 + j];
                s  += v;
                ss += v * v;
            }
            const int slot = (k - 1) % KS;   // compile-time after unroll
            S  += s  - rS[slot];
            SS += ss - rSS[slot];
            rS[slot] = s; rSS[slot] = ss;
        }
        const float pix_var = (SS - S * S * (1.0f / 49.0f)) * (1.0f / 48.0f);
        const float center  = tile[(ty0 + 3 + k) * TSTRIDE + tx + 4];

        acc_r  += center;
        acc_r2 += center * center;
        acc_c  += pix_var * center;
    }

    // --- block reduce 3 floats (wave shuffle -> LDS -> thread 0) ---
#pragma unroll
    for (int off = 32; off > 0; off >>= 1) {
        acc_r  += __shfl_down(acc_r,  off);
        acc_r2 += __shfl_down(acc_r2, off);
        acc_c  += __shfl_down(acc_c,  off);
    }
    __shared__ float sh_r[4], sh_r2[4], sh_c[4];
    const int lane = tid & 63;
    const int wave = tid >> 6;
    if (lane == 0) { sh_r[wave] = acc_r; sh_r2[wave] = acc_r2; sh_c[wave] = acc_c; }
    __syncthreads();
    if (tid == 0) {
        pr [bid] = sh_r [0] + sh_r [1] + sh_r [2] + sh_r [3];
        pr2[bid] = sh_r2[0] + sh_r2[1] + sh_r2[2] + sh_r2[3];
        pc [bid] = sh_c [0] + sh_c [1] + sh_c [2] + sh_c [3];
    }
}

// ---------------------------------------------------------------------------
// Finalize: wave w reduces image w's 64 partials in double; lane 0 applies
// pw_n = pvar^0.2; thread 0 sums the 16 images and writes the scalar.
// ---------------------------------------------------------------------------
__global__ void k_final(const float* __restrict__ pr,
                        const float* __restrict__ pr2,
                        const float* __restrict__ pc,
                        float* __restrict__ out) {
    __shared__ double sh[N_IMG];
    const int tid  = threadIdx.x;       // 1024 threads = 16 waves
    const int w    = tid >> 6;          // image index
    const int lane = tid & 63;

    const int idx = w * TILES_PER_IMG + lane;
    double R  = (double)pr [idx];
    double R2 = (double)pr2[idx];
    double Cs = (double)pc [idx];
#pragma unroll
    for (int off = 32; off > 0; off >>= 1) {
        R  += __shfl_down(R,  off);
        R2 += __shfl_down(R2, off);
        Cs += __shfl_down(Cs, off);
    }
    if (lane == 0) {
        const double pvar = (R2 - R * R / (double)HW) / (double)(HW - 1);
        sh[w] = pow(pvar, 0.2) * Cs;
    }
    __syncthreads();
    if (tid == 0) {
        double s = 0.0;
        for (int i = 0; i < N_IMG; ++i) s += sh[i];
        out[0] = (float)(s / ((double)N_IMG * C_CH * HW));
    }
}

extern "C" void kernel_launch(void* const* d_in, const int* in_sizes, int n_in,
                              void* d_out, int out_size, void* d_ws, size_t ws_size,
                              hipStream_t stream) {
    const float* pred = (const float*)d_in[0];
    const float* targ = (const float*)d_in[1];

    float* pr  = (float*)d_ws;
    float* pr2 = pr  + NBLOCKS;
    float* pc  = pr2 + NBLOCKS;
    float* out = (float*)d_out;

    k_fused<<<NBLOCKS, TPB, 0, stream>>>(pred, targ, pr, pr2, pc);
    k_final<<<1, 1024, 0, stream>>>(pr, pr2, pc, out);
}